// Round 4
// baseline (482.868 us; speedup 1.0000x reference)
//
#include <hip/hip_runtime.h>
#include <math.h>

// VQ-VAE vector quantize, fp32.
// z: (16, 64, 64, 64)  [B, C=64, H, W] ; embed_weight: (1024, 64)
// rows N = 65536 (b, h, w) with channel gathered at stride H*W.
//
// d_out layout (fp32, concatenated in return order):
//   [0, 4194304)               quantize_out (B,C,H,W)  = zp + (q - zp), literal fp32
//   [4194304]                  vq_loss
//   [4194305]                  perplexity
//   [4194306, 4194306+2^26)    embed_onehot (65536, 1024)
//   [71303170, +65536)         embed_index (stored as float)
//
// d_ws layout: int hist[1024] @0 ; float loss @ float-idx 1024 ; float C[1024] @ float-idx 1028
//
// Numerics: replicate numpy float32 semantics for the distance so argmin ties
// resolve identically: A=pairwise(z*z), C=pairwise(w*w) (numpy 8-acc pattern),
// B=sequential-k FMA chain (BLAS microkernel order), dist=(A-2B)+C with
// explicit _rn intrinsics; ties -> lowest code index (np.argmin).

#define HW 4096
#define OUT_Q    0ull
#define OUT_LOSS 4194304ull
#define OUT_PERP 4194305ull
#define OUT_OH   4194306ull
#define OUT_IDX  71303170ull
#define CHUNK 256
#define NCHUNK 4

__global__ void vq_setup(const float* __restrict__ W,
                         float* __restrict__ wsf, int* __restrict__ wsi) {
    const int b = blockIdx.x, tid = threadIdx.x;
    if (tid < 64) wsi[b * 64 + tid] = 0;
    if (b == 0 && tid == 0) wsf[1024] = 0.0f;
    const int wave = tid >> 6, lane = tid & 63;
    // C[code] = numpy-pairwise sum of squares of one codebook row (64 elems).
    for (int p = 0; p < 16; ++p) {
        const int code = b * 64 + p * 4 + wave;
        const float a = W[code * 64 + lane];
        const float sq = __fmul_rn(a, a);
        float t = sq;                       // lanes 0..7 accumulate r[j] = sum_{i = j mod 8}
        #pragma unroll
        for (int m = 1; m < 8; ++m) t = __fadd_rn(t, __shfl(sq, lane + 8 * m, 64));
        const float u  = __fadd_rn(t, __shfl_xor(t, 1, 64));
        const float v  = __fadd_rn(u, __shfl_xor(u, 2, 64));
        const float w2 = __fadd_rn(v, __shfl_xor(v, 4, 64));   // ((r0+r1)+(r2+r3))+((r4+r5)+(r6+r7))
        if (lane == 0) wsf[1028 + code] = w2;
    }
}

__global__ __launch_bounds__(256, 2)
void vq_main(const float* __restrict__ Z, const float* __restrict__ W,
             float* __restrict__ out, float* __restrict__ wsf, int* __restrict__ wsi) {
    // LDS: [0,16384) codebook chunk (256 codes x 64) -- broadcast-read, later
    // aliased as qT[64][65]; [16384,17408) C; then candidates + minidx.
    __shared__ __align__(16) float smem[17984];   // 71.9 KB -> 2 blocks/CU
    float* ldsW   = smem;
    float* ldsC   = smem + 16384;
    float* cand_v = smem + 17408;
    int*   cand_i = (int*)(smem + 17664);
    int*   mi     = (int*)(smem + 17920);

    const int tid  = threadIdx.x;
    const int wave = tid >> 6;
    const int lane = tid & 63;
    const int blk  = blockIdx.x;
    const int b    = blk >> 6;
    const int hw0  = (blk & 63) << 6;
    const int rowbase = b * HW + hw0;

    // stage chunk 0 (64 KB, L2-resident codebook)
    {
        const float4* gs = (const float4*)W;
        float4* ls = (float4*)ldsW;
        #pragma unroll
        for (int i = 0; i < 16; ++i) ls[i * 256 + tid] = gs[i * 256 + tid];
    }
    // code norms into LDS (1024 floats)
    ((float4*)ldsC)[tid] = ((const float4*)(wsf + 1028))[tid];

    // z row of this lane into registers (coalesced: lane = consecutive hw)
    const float* zb = Z + (size_t)b * 64 * HW + hw0 + lane;
    float zr[64];
    #pragma unroll
    for (int c = 0; c < 64; ++c) zr[c] = zb[(size_t)c * HW];

    // A = numpy-pairwise sum of z*z
    float r[8];
    #pragma unroll
    for (int j = 0; j < 8; ++j) r[j] = __fmul_rn(zr[j], zr[j]);
    #pragma unroll
    for (int i = 8; i < 64; i += 8) {
        #pragma unroll
        for (int j = 0; j < 8; ++j) r[j] = __fadd_rn(r[j], __fmul_rn(zr[i + j], zr[i + j]));
    }
    const float A = __fadd_rn(__fadd_rn(__fadd_rn(r[0], r[1]), __fadd_rn(r[2], r[3])),
                              __fadd_rn(__fadd_rn(r[4], r[5]), __fadd_rn(r[6], r[7])));

    float bestv = __builtin_huge_valf();
    int   besti = 0;

    for (int ch = 0; ch < NCHUNK; ++ch) {
        __syncthreads();                         // chunk staged, everyone ready
        #pragma unroll 2
        for (int cc = 0; cc < 64; ++cc) {
            const int cl = cc * 4 + wave;        // wave sweeps codes == wave (mod 4), ascending
            const float* wrow = ldsW + cl * 64;  // wave-uniform address -> LDS broadcast reads
            float dot = 0.0f;
            #pragma unroll
            for (int k4 = 0; k4 < 16; ++k4) {
                const float4 wv = *(const float4*)(wrow + k4 * 4);
                dot = __fmaf_rn(zr[4 * k4 + 0], wv.x, dot);
                dot = __fmaf_rn(zr[4 * k4 + 1], wv.y, dot);
                dot = __fmaf_rn(zr[4 * k4 + 2], wv.z, dot);
                dot = __fmaf_rn(zr[4 * k4 + 3], wv.w, dot);
            }
            const int code = ch * CHUNK + cl;
            const float d = __fadd_rn(__fsub_rn(A, 2.0f * dot), ldsC[code]);
            if (d < bestv) { bestv = d; besti = code; }   // strict < keeps first (lowest) index
        }
        if (ch + 1 < NCHUNK) {
            __syncthreads();                     // all waves done reading before overwrite
            const float4* gs = (const float4*)(W + (size_t)(ch + 1) * CHUNK * 64);
            float4* ls = (float4*)ldsW;
            #pragma unroll
            for (int i = 0; i < 16; ++i) ls[i * 256 + tid] = gs[i * 256 + tid];
        }
    }

    // combine the 4 interleaved code-groups per row; ties -> lowest index
    cand_v[wave * 64 + lane] = bestv;
    cand_i[wave * 64 + lane] = besti;
    __syncthreads();
    if (wave == 0) {
        float bv = cand_v[lane]; int bi = cand_i[lane];
        #pragma unroll
        for (int s = 1; s < 4; ++s) {
            const float v  = cand_v[s * 64 + lane];
            const int   i2 = cand_i[s * 64 + lane];
            if (v < bv || (v == bv && i2 < bi)) { bv = v; bi = i2; }
        }
        mi[lane] = bi;
        out[OUT_IDX + rowbase + lane] = (float)bi;
        atomicAdd(&wsi[bi], 1);
    }
    __syncthreads();

    // gather quantize rows into qT (aliases ldsW; stride 65 -> conflict-free transpose)
    float* qT = smem;
    {
        const int m = mi[lane];
        const float4* wq = (const float4*)(W + m * 64);
        #pragma unroll
        for (int j4 = 0; j4 < 4; ++j4) {
            const float4 q = wq[wave * 4 + j4];
            const int c0 = wave * 16 + j4 * 4;
            qT[lane * 65 + c0 + 0] = q.x;
            qT[lane * 65 + c0 + 1] = q.y;
            qT[lane * 65 + c0 + 2] = q.z;
            qT[lane * 65 + c0 + 3] = q.w;
        }
    }
    __syncthreads();

    // transposed store of quantize_st = z + (q - z) (literal fp32, matches ref)
    // + loss partial using the shared (q - z) term; z comes from registers.
    float lsum = 0.0f;
    #pragma unroll
    for (int j = 0; j < 16; ++j) {
        const int c = j * 4 + wave;
        const float qv = qT[lane * 65 + c];
        const float zv = zr[c];
        const float dd = __fsub_rn(qv, zv);
        lsum = __fmaf_rn(dd, dd, lsum);
        out[OUT_Q + (size_t)(b * 64 + c) * HW + hw0 + lane] = __fadd_rn(zv, dd);
    }
    #pragma unroll
    for (int s = 32; s > 0; s >>= 1) lsum += __shfl_xor(lsum, s, 64);
    if (lane == 0) atomicAdd(wsf + 1024, lsum);

    // onehot rows (256 KB per block; float2: region is only 8B-aligned)
    for (int i = 0; i < 64; ++i) {
        const int m = mi[i];
        float* basep = out + OUT_OH + (size_t)(rowbase + i) * 1024;
        const int c0 = tid * 2;
        float2 v0, v1;
        v0.x = (c0       == m) ? 1.0f : 0.0f;
        v0.y = (c0 + 1   == m) ? 1.0f : 0.0f;
        v1.x = (c0 + 512 == m) ? 1.0f : 0.0f;
        v1.y = (c0 + 513 == m) ? 1.0f : 0.0f;
        *(float2*)(basep + c0)       = v0;
        *(float2*)(basep + 512 + c0) = v1;
    }
}

__global__ void vq_final(const int* __restrict__ wsi, const float* __restrict__ wsf,
                         float* __restrict__ out) {
    __shared__ double red[256];
    const int tid = threadIdx.x;
    double s = 0.0;
    for (int j = tid; j < 1024; j += 256) {
        const float e  = (float)wsi[j] * (1.0f / 65536.0f);   // exact
        const float lg = logf(__fadd_rn(e, 1e-10f));
        s += (double)__fmul_rn(e, lg);
    }
    red[tid] = s;
    __syncthreads();
    for (int st = 128; st > 0; st >>= 1) {
        if (tid < st) red[tid] += red[tid + st];
        __syncthreads();
    }
    if (tid == 0) {
        out[OUT_PERP] = expf((float)(-red[0]));
        const float ms = wsf[1024] * (1.0f / 4194304.0f);
        out[OUT_LOSS] = __fadd_rn(ms, __fmul_rn(0.25f, ms));   // m + 0.25*m
    }
}

extern "C" void kernel_launch(void* const* d_in, const int* in_sizes, int n_in,
                              void* d_out, int out_size, void* d_ws, size_t ws_size,
                              hipStream_t stream) {
    const float* Z = (const float*)d_in[0];
    const float* W = (const float*)d_in[1];
    float* out = (float*)d_out;
    float* wsf = (float*)d_ws;
    int*   wsi = (int*)d_ws;
    vq_setup<<<16,   256, 0, stream>>>(W, wsf, wsi);
    vq_main <<<1024, 256, 0, stream>>>(Z, W, out, wsf, wsi);
    vq_final<<<1,    256, 0, stream>>>(wsi, wsf, out);
}

// Round 6
// 461.517 us; speedup vs baseline: 1.0463x; 1.0463x over previous
//
#include <hip/hip_runtime.h>
#include <math.h>

// VQ-VAE vector quantize, fp32.
// z: (16, 64, 64, 64)  [B, C=64, H, W] ; embed_weight: (1024, 64)
// rows N = 65536 (b, h, w) with channel gathered at stride H*W.
//
// Round-5 change (theory: DS-pipe bound on broadcast ds_read_b128):
// codebook reads moved from LDS staging to the scalar memory pipe via
// inline-asm s_load_dwordx16 (wave-uniform rows -> SGPRs). DS pipe freed;
// VALU (FMA chain) + mandatory 347 MB store drain become the limiters.
// Numerics bit-identical to the passing round-4 kernel.
//
// d_out layout (fp32, concatenated in return order):
//   [0, 4194304)               quantize_out = zp + (q - zp), literal fp32
//   [4194304]                  vq_loss
//   [4194305]                  perplexity
//   [4194306, 4194306+2^26)    embed_onehot (65536, 1024)
//   [71303170, +65536)         embed_index (stored as float)
//
// d_ws: int hist[1024] @0 ; float loss @ f-idx 1024 ; float C[1024] @ f-idx 1028

#define HW 4096
#define OUT_Q    0ull
#define OUT_LOSS 4194304ull
#define OUT_PERP 4194305ull
#define OUT_OH   4194306ull
#define OUT_IDX  71303170ull

typedef float f32x16 __attribute__((ext_vector_type(16)));

__global__ void vq_setup(const float* __restrict__ W,
                         float* __restrict__ wsf, int* __restrict__ wsi) {
    const int b = blockIdx.x, tid = threadIdx.x;
    if (tid < 64) wsi[b * 64 + tid] = 0;
    if (b == 0 && tid == 0) wsf[1024] = 0.0f;
    const int wave = tid >> 6, lane = tid & 63;
    // C[code] = numpy-pairwise sum of squares of one codebook row (64 elems).
    for (int p = 0; p < 16; ++p) {
        const int code = b * 64 + p * 4 + wave;
        const float a = W[code * 64 + lane];
        const float sq = __fmul_rn(a, a);
        float t = sq;                       // lanes 0..7: r[j] = sum_{i = j mod 8}
        #pragma unroll
        for (int m = 1; m < 8; ++m) t = __fadd_rn(t, __shfl(sq, lane + 8 * m, 64));
        const float u  = __fadd_rn(t, __shfl_xor(t, 1, 64));
        const float v  = __fadd_rn(u, __shfl_xor(u, 2, 64));
        const float w2 = __fadd_rn(v, __shfl_xor(v, 4, 64));   // ((r0+r1)+(r2+r3))+((r4+r5)+(r6+r7))
        if (lane == 0) wsf[1028 + code] = w2;
    }
}

__global__ __launch_bounds__(256, 4)
void vq_main(const float* __restrict__ Z, const float* __restrict__ W,
             float* __restrict__ out, float* __restrict__ wsf, int* __restrict__ wsi) {
    // LDS (23 KB -> 4 blocks/CU): qT transpose + C norms + argmin scratch.
    __shared__ __align__(16) float qT[64 * 65];      // stride 65: conflict-free
    __shared__ __align__(16) float ldsC[1024];
    __shared__ float cand_v[256];
    __shared__ int   cand_i[256];
    __shared__ int   mi[64];

    const int tid  = threadIdx.x;
    const int wave = tid >> 6;
    const int lane = tid & 63;
    const int blk  = blockIdx.x;
    const int b    = blk >> 6;
    const int hw0  = (blk & 63) << 6;
    const int rowbase = b * HW + hw0;

    // code norms into LDS (1024 floats, 16B-aligned src)
    ((float4*)ldsC)[tid] = ((const float4*)(wsf + 1028))[tid];

    // z row of this lane into registers (coalesced: lane = consecutive hw)
    const float* zb = Z + (size_t)b * 64 * HW + hw0 + lane;
    float zr[64];
    #pragma unroll
    for (int c = 0; c < 64; ++c) zr[c] = zb[(size_t)c * HW];

    // A = numpy-pairwise sum of z*z
    float r[8];
    #pragma unroll
    for (int j = 0; j < 8; ++j) r[j] = __fmul_rn(zr[j], zr[j]);
    #pragma unroll
    for (int i = 8; i < 64; i += 8) {
        #pragma unroll
        for (int j = 0; j < 8; ++j) r[j] = __fadd_rn(r[j], __fmul_rn(zr[i + j], zr[i + j]));
    }
    const float A = __fadd_rn(__fadd_rn(__fadd_rn(r[0], r[1]), __fadd_rn(r[2], r[3])),
                              __fadd_rn(__fadd_rn(r[4], r[5]), __fadd_rn(r[6], r[7])));

    __syncthreads();                                 // ldsC staged

    // Wave-uniform codebook base for this wave's code subset (code % 4 == wave).
    const float* Wwave = (const float*)((const char*)W +
                         __builtin_amdgcn_readfirstlane(wave << 8));

    float bestv = __builtin_huge_valf();
    int   besti = 0;

    for (int i = 0; i < 256; ++i) {
        const int code = i * 4 + wave;               // ascending -> first-min = lowest idx
        const float* wrow = (const float*)((const char*)Wwave + (i << 10));
        f32x16 a0, a1, a2, a3;                       // 64 SGPRs, one codebook row
        asm volatile(
            "s_load_dwordx16 %0, %4, 0x0\n\t"
            "s_load_dwordx16 %1, %4, 0x40\n\t"
            "s_load_dwordx16 %2, %4, 0x80\n\t"
            "s_load_dwordx16 %3, %4, 0xc0\n\t"
            "s_waitcnt lgkmcnt(0)"
            : "=&s"(a0), "=&s"(a1), "=&s"(a2), "=&s"(a3)
            : "s"(wrow));
        // sequential-k FMA chain, identical order/values to the passing kernel
        float dot = 0.0f;
        #pragma unroll
        for (int k = 0; k < 16; ++k) dot = __fmaf_rn(zr[k],      a0[k], dot);
        #pragma unroll
        for (int k = 0; k < 16; ++k) dot = __fmaf_rn(zr[16 + k], a1[k], dot);
        #pragma unroll
        for (int k = 0; k < 16; ++k) dot = __fmaf_rn(zr[32 + k], a2[k], dot);
        #pragma unroll
        for (int k = 0; k < 16; ++k) dot = __fmaf_rn(zr[48 + k], a3[k], dot);
        const float d = __fadd_rn(__fsub_rn(A, 2.0f * dot), ldsC[code]);
        if (d < bestv) { bestv = d; besti = code; }  // strict < keeps lowest index
    }

    // combine the 4 interleaved code-groups per row; ties -> lowest index
    cand_v[wave * 64 + lane] = bestv;
    cand_i[wave * 64 + lane] = besti;
    __syncthreads();
    if (wave == 0) {
        float bv = cand_v[lane]; int bi = cand_i[lane];
        #pragma unroll
        for (int s = 1; s < 4; ++s) {
            const float v  = cand_v[s * 64 + lane];
            const int   i2 = cand_i[s * 64 + lane];
            if (v < bv || (v == bv && i2 < bi)) { bv = v; bi = i2; }
        }
        mi[lane] = bi;
        out[OUT_IDX + rowbase + lane] = (float)bi;
        atomicAdd(&wsi[bi], 1);
    }
    __syncthreads();

    // gather quantize rows into qT (per-lane codes, L2-hot vector loads)
    {
        const int m = mi[lane];
        const float4* wq = (const float4*)(W + m * 64);
        #pragma unroll
        for (int j4 = 0; j4 < 4; ++j4) {
            const float4 q = wq[wave * 4 + j4];
            const int c0 = wave * 16 + j4 * 4;
            qT[lane * 65 + c0 + 0] = q.x;
            qT[lane * 65 + c0 + 1] = q.y;
            qT[lane * 65 + c0 + 2] = q.z;
            qT[lane * 65 + c0 + 3] = q.w;
        }
    }
    __syncthreads();

    // transposed store of quantize_st = z + (q - z) (literal fp32, matches ref)
    // + loss partial using the shared (q - z) term; z still in registers.
    float lsum = 0.0f;
    #pragma unroll
    for (int j = 0; j < 16; ++j) {
        const int c = j * 4 + wave;
        const float qv = qT[lane * 65 + c];
        const float zv = zr[c];
        const float dd = __fsub_rn(qv, zv);
        lsum = __fmaf_rn(dd, dd, lsum);
        out[OUT_Q + (size_t)(b * 64 + c) * HW + hw0 + lane] = __fadd_rn(zv, dd);
    }
    #pragma unroll
    for (int s = 32; s > 0; s >>= 1) lsum += __shfl_xor(lsum, s, 64);
    if (lane == 0) atomicAdd(wsf + 1024, lsum);

    // onehot rows (256 KB per block; float2: region is only 8B-aligned)
    for (int i = 0; i < 64; ++i) {
        const int m = mi[i];
        float* basep = out + OUT_OH + (size_t)(rowbase + i) * 1024;
        const int c0 = tid * 2;
        float2 v0, v1;
        v0.x = (c0       == m) ? 1.0f : 0.0f;
        v0.y = (c0 + 1   == m) ? 1.0f : 0.0f;
        v1.x = (c0 + 512 == m) ? 1.0f : 0.0f;
        v1.y = (c0 + 513 == m) ? 1.0f : 0.0f;
        *(float2*)(basep + c0)       = v0;
        *(float2*)(basep + 512 + c0) = v1;
    }
}

__global__ void vq_final(const int* __restrict__ wsi, const float* __restrict__ wsf,
                         float* __restrict__ out) {
    __shared__ double red[256];
    const int tid = threadIdx.x;
    double s = 0.0;
    for (int j = tid; j < 1024; j += 256) {
        const float e  = (float)wsi[j] * (1.0f / 65536.0f);   // exact
        const float lg = logf(__fadd_rn(e, 1e-10f));
        s += (double)__fmul_rn(e, lg);
    }
    red[tid] = s;
    __syncthreads();
    for (int st = 128; st > 0; st >>= 1) {
        if (tid < st) red[tid] += red[tid + st];
        __syncthreads();
    }
    if (tid == 0) {
        out[OUT_PERP] = expf((float)(-red[0]));
        const float ms = wsf[1024] * (1.0f / 4194304.0f);
        out[OUT_LOSS] = __fadd_rn(ms, __fmul_rn(0.25f, ms));   // m + 0.25*m
    }
}

extern "C" void kernel_launch(void* const* d_in, const int* in_sizes, int n_in,
                              void* d_out, int out_size, void* d_ws, size_t ws_size,
                              hipStream_t stream) {
    const float* Z = (const float*)d_in[0];
    const float* W = (const float*)d_in[1];
    float* out = (float*)d_out;
    float* wsf = (float*)d_ws;
    int*   wsi = (int*)d_ws;
    vq_setup<<<16,   256, 0, stream>>>(W, wsf, wsi);
    vq_main <<<1024, 256, 0, stream>>>(Z, W, out, wsf, wsi);
    vq_final<<<1,    256, 0, stream>>>(wsi, wsf, out);
}

// Round 7
// 461.403 us; speedup vs baseline: 1.0465x; 1.0002x over previous
//
#include <hip/hip_runtime.h>
#include <math.h>

// VQ-VAE vector quantize, fp32.
// z: (16, 64, 64, 64)  [B, C=64, H, W] ; embed_weight: (1024, 64)
// rows N = 65536 (b, h, w) with channel gathered at stride H*W.
//
// Round-6 post-mortem: __launch_bounds__(256,4) made the compiler park zr[64]
// in AGPRs (VGPR_Count=40) -> one v_accvgpr_read per FMA operand ~doubled VALU
// issue (VALUBusy*dur = 131us vs 55us FMA floor). Round-7 change: budget
// (256,2) so zr stays in arch VGPRs; actual use ~100 VGPR still gives 4-5
// waves/SIMD for SMEM latency hiding. Numerics bit-identical.
//
// d_out layout (fp32, concatenated in return order):
//   [0, 4194304)               quantize_out = zp + (q - zp), literal fp32
//   [4194304]                  vq_loss
//   [4194305]                  perplexity
//   [4194306, 4194306+2^26)    embed_onehot (65536, 1024)
//   [71303170, +65536)         embed_index (stored as float)
//
// d_ws: int hist[1024] @0 ; float loss @ f-idx 1024 ; float C[1024] @ f-idx 1028

#define HW 4096
#define OUT_Q    0ull
#define OUT_LOSS 4194304ull
#define OUT_PERP 4194305ull
#define OUT_OH   4194306ull
#define OUT_IDX  71303170ull

typedef float f32x16 __attribute__((ext_vector_type(16)));

__global__ void vq_setup(const float* __restrict__ W,
                         float* __restrict__ wsf, int* __restrict__ wsi) {
    const int b = blockIdx.x, tid = threadIdx.x;
    if (tid < 64) wsi[b * 64 + tid] = 0;
    if (b == 0 && tid == 0) wsf[1024] = 0.0f;
    const int wave = tid >> 6, lane = tid & 63;
    // C[code] = numpy-pairwise sum of squares of one codebook row (64 elems).
    for (int p = 0; p < 16; ++p) {
        const int code = b * 64 + p * 4 + wave;
        const float a = W[code * 64 + lane];
        const float sq = __fmul_rn(a, a);
        float t = sq;                       // lanes 0..7: r[j] = sum_{i = j mod 8}
        #pragma unroll
        for (int m = 1; m < 8; ++m) t = __fadd_rn(t, __shfl(sq, lane + 8 * m, 64));
        const float u  = __fadd_rn(t, __shfl_xor(t, 1, 64));
        const float v  = __fadd_rn(u, __shfl_xor(u, 2, 64));
        const float w2 = __fadd_rn(v, __shfl_xor(v, 4, 64));   // ((r0+r1)+(r2+r3))+((r4+r5)+(r6+r7))
        if (lane == 0) wsf[1028 + code] = w2;
    }
}

__global__ __launch_bounds__(256, 2)
void vq_main(const float* __restrict__ Z, const float* __restrict__ W,
             float* __restrict__ out, float* __restrict__ wsf, int* __restrict__ wsi) {
    // LDS (23 KB): qT transpose + C norms + argmin scratch.
    __shared__ __align__(16) float qT[64 * 65];      // stride 65: conflict-free
    __shared__ __align__(16) float ldsC[1024];
    __shared__ float cand_v[256];
    __shared__ int   cand_i[256];
    __shared__ int   mi[64];

    const int tid  = threadIdx.x;
    const int wave = tid >> 6;
    const int lane = tid & 63;
    const int blk  = blockIdx.x;
    const int b    = blk >> 6;
    const int hw0  = (blk & 63) << 6;
    const int rowbase = b * HW + hw0;

    // code norms into LDS (1024 floats, 16B-aligned src)
    ((float4*)ldsC)[tid] = ((const float4*)(wsf + 1028))[tid];

    // z row of this lane into registers (coalesced: lane = consecutive hw)
    const float* zb = Z + (size_t)b * 64 * HW + hw0 + lane;
    float zr[64];
    #pragma unroll
    for (int c = 0; c < 64; ++c) zr[c] = zb[(size_t)c * HW];

    // A = numpy-pairwise sum of z*z
    float r[8];
    #pragma unroll
    for (int j = 0; j < 8; ++j) r[j] = __fmul_rn(zr[j], zr[j]);
    #pragma unroll
    for (int i = 8; i < 64; i += 8) {
        #pragma unroll
        for (int j = 0; j < 8; ++j) r[j] = __fadd_rn(r[j], __fmul_rn(zr[i + j], zr[i + j]));
    }
    const float A = __fadd_rn(__fadd_rn(__fadd_rn(r[0], r[1]), __fadd_rn(r[2], r[3])),
                              __fadd_rn(__fadd_rn(r[4], r[5]), __fadd_rn(r[6], r[7])));

    __syncthreads();                                 // ldsC staged

    // Wave-uniform codebook base for this wave's code subset (code % 4 == wave).
    const float* Wwave = (const float*)((const char*)W +
                         __builtin_amdgcn_readfirstlane(wave << 8));

    float bestv = __builtin_huge_valf();
    int   besti = 0;

    for (int i = 0; i < 256; ++i) {
        const int code = i * 4 + wave;               // ascending -> first-min = lowest idx
        const float* wrow = (const float*)((const char*)Wwave + (i << 10));
        f32x16 a0, a1, a2, a3;                       // 64 SGPRs, one codebook row
        asm volatile(
            "s_load_dwordx16 %0, %4, 0x0\n\t"
            "s_load_dwordx16 %1, %4, 0x40\n\t"
            "s_load_dwordx16 %2, %4, 0x80\n\t"
            "s_load_dwordx16 %3, %4, 0xc0\n\t"
            "s_waitcnt lgkmcnt(0)"
            : "=&s"(a0), "=&s"(a1), "=&s"(a2), "=&s"(a3)
            : "s"(wrow));
        // sequential-k FMA chain, identical order/values to the passing kernel
        float dot = 0.0f;
        #pragma unroll
        for (int k = 0; k < 16; ++k) dot = __fmaf_rn(zr[k],      a0[k], dot);
        #pragma unroll
        for (int k = 0; k < 16; ++k) dot = __fmaf_rn(zr[16 + k], a1[k], dot);
        #pragma unroll
        for (int k = 0; k < 16; ++k) dot = __fmaf_rn(zr[32 + k], a2[k], dot);
        #pragma unroll
        for (int k = 0; k < 16; ++k) dot = __fmaf_rn(zr[48 + k], a3[k], dot);
        const float d = __fadd_rn(__fsub_rn(A, 2.0f * dot), ldsC[code]);
        if (d < bestv) { bestv = d; besti = code; }  // strict < keeps lowest index
    }

    // combine the 4 interleaved code-groups per row; ties -> lowest index
    cand_v[wave * 64 + lane] = bestv;
    cand_i[wave * 64 + lane] = besti;
    __syncthreads();
    if (wave == 0) {
        float bv = cand_v[lane]; int bi = cand_i[lane];
        #pragma unroll
        for (int s = 1; s < 4; ++s) {
            const float v  = cand_v[s * 64 + lane];
            const int   i2 = cand_i[s * 64 + lane];
            if (v < bv || (v == bv && i2 < bi)) { bv = v; bi = i2; }
        }
        mi[lane] = bi;
        out[OUT_IDX + rowbase + lane] = (float)bi;
        atomicAdd(&wsi[bi], 1);
    }
    __syncthreads();

    // gather quantize rows into qT (per-lane codes, L2-hot vector loads)
    {
        const int m = mi[lane];
        const float4* wq = (const float4*)(W + m * 64);
        #pragma unroll
        for (int j4 = 0; j4 < 4; ++j4) {
            const float4 q = wq[wave * 4 + j4];
            const int c0 = wave * 16 + j4 * 4;
            qT[lane * 65 + c0 + 0] = q.x;
            qT[lane * 65 + c0 + 1] = q.y;
            qT[lane * 65 + c0 + 2] = q.z;
            qT[lane * 65 + c0 + 3] = q.w;
        }
    }
    __syncthreads();

    // transposed store of quantize_st = z + (q - z) (literal fp32, matches ref)
    // + loss partial using the shared (q - z) term; z still in registers.
    float lsum = 0.0f;
    #pragma unroll
    for (int j = 0; j < 16; ++j) {
        const int c = j * 4 + wave;
        const float qv = qT[lane * 65 + c];
        const float zv = zr[c];
        const float dd = __fsub_rn(qv, zv);
        lsum = __fmaf_rn(dd, dd, lsum);
        out[OUT_Q + (size_t)(b * 64 + c) * HW + hw0 + lane] = __fadd_rn(zv, dd);
    }
    #pragma unroll
    for (int s = 32; s > 0; s >>= 1) lsum += __shfl_xor(lsum, s, 64);
    if (lane == 0) atomicAdd(wsf + 1024, lsum);

    // onehot rows (256 KB per block; float2: region is only 8B-aligned)
    for (int i = 0; i < 64; ++i) {
        const int m = mi[i];
        float* basep = out + OUT_OH + (size_t)(rowbase + i) * 1024;
        const int c0 = tid * 2;
        float2 v0, v1;
        v0.x = (c0       == m) ? 1.0f : 0.0f;
        v0.y = (c0 + 1   == m) ? 1.0f : 0.0f;
        v1.x = (c0 + 512 == m) ? 1.0f : 0.0f;
        v1.y = (c0 + 513 == m) ? 1.0f : 0.0f;
        *(float2*)(basep + c0)       = v0;
        *(float2*)(basep + 512 + c0) = v1;
    }
}

__global__ void vq_final(const int* __restrict__ wsi, const float* __restrict__ wsf,
                         float* __restrict__ out) {
    __shared__ double red[256];
    const int tid = threadIdx.x;
    double s = 0.0;
    for (int j = tid; j < 1024; j += 256) {
        const float e  = (float)wsi[j] * (1.0f / 65536.0f);   // exact
        const float lg = logf(__fadd_rn(e, 1e-10f));
        s += (double)__fmul_rn(e, lg);
    }
    red[tid] = s;
    __syncthreads();
    for (int st = 128; st > 0; st >>= 1) {
        if (tid < st) red[tid] += red[tid + st];
        __syncthreads();
    }
    if (tid == 0) {
        out[OUT_PERP] = expf((float)(-red[0]));
        const float ms = wsf[1024] * (1.0f / 4194304.0f);
        out[OUT_LOSS] = __fadd_rn(ms, __fmul_rn(0.25f, ms));   // m + 0.25*m
    }
}

extern "C" void kernel_launch(void* const* d_in, const int* in_sizes, int n_in,
                              void* d_out, int out_size, void* d_ws, size_t ws_size,
                              hipStream_t stream) {
    const float* Z = (const float*)d_in[0];
    const float* W = (const float*)d_in[1];
    float* out = (float*)d_out;
    float* wsf = (float*)d_ws;
    int*   wsi = (int*)d_ws;
    vq_setup<<<16,   256, 0, stream>>>(W, wsf, wsi);
    vq_main <<<1024, 256, 0, stream>>>(Z, W, out, wsf, wsi);
    vq_final<<<1,    256, 0, stream>>>(wsi, wsf, out);
}